// Round 9
// baseline (110.769 us; speedup 1.0000x reference)
//
#include <hip/hip_runtime.h>
#include <hip/hip_bf16.h>

#define UNITS 64
#define IFEAT 256
#define OFEAT 256

typedef __attribute__((ext_vector_type(8))) short v8s;   // 8 bf16 (4 VGPRs)
typedef __attribute__((ext_vector_type(4))) float v4f;   // MFMA acc / global f32x4

// pack 2 floats -> u32 of 2 bf16 (RNE) — compiler emits v_cvt_pk_bf16_f32
static __device__ __forceinline__ unsigned int pk2(float a, float b) {
    union { __hip_bfloat162 h; unsigned int u; } c;
    c.h = __float22bfloat162_rn(float2{a, b});
    return c.u;
}

static __device__ __forceinline__ float sigmoid_f(float x) {
    return 1.0f / (1.0f + __expf(-x));
}
static __device__ __forceinline__ float tanh_f(float x) {
    float ax = fabsf(x);
    float e = __expf(-2.0f * ax);
    float t = (1.0f - e) / (1.0f + e);
    return copysignf(t, x);
}

// ---------------------------------------------------------------------------
// Single fused kernel: per-unit 3-way MFMA GEMM + interleaved hvec + GRU.
// BM=128, BN=128, BK=32. 1024 threads = 16 waves (4m x 4n), wave tile 32x32.
// A (x tile) full-K resident in LDS (64KB, rotated conflict-free layout).
// B (W_i) double-buffered per K-step (register-transpose, conflict-free b128).
// hvec = hinit . w_h INTERLEAVED into the K-loop: 12 loads + 12 FMAs per
// thread per step (instead of R8's serial prologue burst) -> the 393KB w_h
// slice streams under MFMA/staging work. Partials -> LDS after step 7,
// reduce, epilogue. w_h slice shared with the mb-twin block via XCD L2.
// LDS 125.5KB -> 1 block/CU; grid 256 = 64u x 2mb x 2nb = exactly 1/CU.
// ---------------------------------------------------------------------------
__global__ __launch_bounds__(1024, 4) void gru_fused(
    const float* __restrict__ x,
    const float* __restrict__ wir,
    const float* __restrict__ wiz,
    const float* __restrict__ win,
    const float* __restrict__ whr,
    const float* __restrict__ whz,
    const float* __restrict__ whn,
    const float* __restrict__ hinit,
    float* __restrict__ out) {
    __shared__ unsigned short As[32][128][8];        // [kq][row'][j]        64 KB
    __shared__ unsigned short Bs[2][3][4][128][8];   // [buf][g][kq][col][j] 48 KB
    __shared__ float Ph[8][3][128];                  // hvec partials        12 KB
    __shared__ float Hf[3][128];                     // hvec final          1.5 KB

    const int bid = blockIdx.x;
    // XCD swizzle: xcd = bid&7 owns units [xcd*8, xcd*8+8); 4 blocks/unit.
    const int idx = bid >> 3;                  // 0..31 within XCD
    const int u   = (bid & 7) * 8 + (idx >> 2);
    const int rem = idx & 3;
    const int b0  = (rem >> 1) * 128;          // batch tile 0..1
    const int o0  = (rem & 1) * 128;           // out-feature tile 0..1

    const int t    = threadIdx.x;
    const int lane = t & 63;
    const int wv   = t >> 6;                   // 16 waves: 4m x 4n
    const int wm   = wv >> 2;                  // 0..3
    const int wn   = wv & 3;                   // 0..3
    const int lg   = lane >> 4;                // k-quad within step
    const int lr   = lane & 15;

    // ---- B staging: 1536 col-vectors/step over 1024 threads ----
    const int bcol = t & 127;
    const int bkq  = (t >> 7) & 3;
    const int gA   = t >> 9;                   // wave-uniform (0 or 1)
    const bool hasB = (wv < 8);                // wave-uniform
    const float* wpA = (gA == 0) ? wir : wiz;
    const size_t bgbase = (size_t)u * (IFEAT * OFEAT) + (bkq * 8) * OFEAT + o0 + bcol;

    float rbA[8], rbB[8];

    auto bload = [&](int kk) {
        const size_t off = bgbase + (size_t)kk * 32 * OFEAT;
#pragma unroll
        for (int j = 0; j < 8; ++j) rbA[j] = wpA[off + j * OFEAT];
        if (hasB) {
#pragma unroll
            for (int j = 0; j < 8; ++j) rbB[j] = win[off + j * OFEAT];
        }
    };
    auto bwrite = [&](int bb) {
        uint4 v;
        v.x = pk2(rbA[0], rbA[1]);
        v.y = pk2(rbA[2], rbA[3]);
        v.z = pk2(rbA[4], rbA[5]);
        v.w = pk2(rbA[6], rbA[7]);
        *(uint4*)&Bs[bb][gA][bkq][bcol][0] = v;
        if (hasB) {
            uint4 w;
            w.x = pk2(rbB[0], rbB[1]);
            w.y = pk2(rbB[2], rbB[3]);
            w.z = pk2(rbB[4], rbB[5]);
            w.w = pk2(rbB[6], rbB[7]);
            *(uint4*)&Bs[bb][2][bkq][bcol][0] = w;
        }
    };

    // ---- hvec interleave state ----
    const int ho = t & 127;                    // o-col within slice
    const int hq = t >> 7;                     // i-chunk 0..7 (wave-uniform)
    const float* hp = hinit + u * IFEAT + hq * 32;
    const size_t whbase = (size_t)u * (IFEAT * OFEAT)
                        + (size_t)(hq * 32) * OFEAT + o0 + ho;
    float p0 = 0.f, p1 = 0.f, p2 = 0.f;

    v4f acc[3][2][2];
#pragma unroll
    for (int g = 0; g < 3; ++g)
#pragma unroll
        for (int mi = 0; mi < 2; ++mi)
#pragma unroll
            for (int ni = 0; ni < 2; ++ni)
                acc[g][mi][ni] = (v4f){0.f, 0.f, 0.f, 0.f};

    // ---- prologue ----
    bload(0);                                  // B(0) in flight
    {
        // A-tile: rows coalesced (1KB row per instr), rotated frag layout
        const int kqA = lane >> 1;             // lane owns k = lane*4..+3
        const int j0  = (lane & 1) * 4;
#pragma unroll
        for (int i = 0; i < 8; ++i) {
            const int row = wv * 8 + i;
            v4f q = *(const v4f*)(x + (size_t)(b0 + row) * (UNITS * IFEAT)
                                    + u * IFEAT + lane * 4);
            uint2 w;
            w.x = pk2(q[0], q[1]);
            w.y = pk2(q[2], q[3]);
            *(uint2*)&As[kqA][(row + kqA) & 127][j0] = w;
        }
    }
    bwrite(0);
    bload(1);
    __syncthreads();

    // ---- K-loop: 8 steps, dbuf B, 1 barrier/step, hvec interleaved ----
#pragma unroll
    for (int kk = 0; kk < 8; ++kk) {
        const int bb = kk & 1;
        if (kk < 7) bwrite(bb ^ 1);        // data for kk+1 into other buffer
        if (kk < 6) bload(kk + 2);         // refill regs; lands under MFMAs

        // hvec slice for this step: 4 i-values x 3 gates (loads ride with
        // the step's other VMEM; FMAs fill VALU gaps under MFMAs)
        {
            const size_t off0 = whbase + (size_t)(kk * 4) * OFEAT;
#pragma unroll
            for (int ii = 0; ii < 4; ++ii) {
                const float hi = hp[kk * 4 + ii];          // scalar (uniform)
                const size_t off = off0 + (size_t)ii * OFEAT;
                p0 += hi * whr[off];
                p1 += hi * whz[off];
                p2 += hi * whn[off];
            }
        }

        const int kq0 = kk * 4 + lg;
        v8s a0 = *(const v8s*)&As[kq0][((wm * 32 + lr) + kq0) & 127][0];
        v8s a1 = *(const v8s*)&As[kq0][((wm * 32 + 16 + lr) + kq0) & 127][0];
#pragma unroll
        for (int g = 0; g < 3; ++g) {
#pragma unroll
            for (int ni = 0; ni < 2; ++ni) {
                v8s b = *(const v8s*)&Bs[bb][g][lg][wn * 32 + ni * 16 + lr][0];
                acc[g][0][ni] = __builtin_amdgcn_mfma_f32_16x16x32_bf16(a0, b, acc[g][0][ni], 0, 0, 0);
                acc[g][1][ni] = __builtin_amdgcn_mfma_f32_16x16x32_bf16(a1, b, acc[g][1][ni], 0, 0, 0);
            }
        }
        if (kk < 7) __syncthreads();       // writes(bb^1) visible, reads(bb) done
    }

    // ---- hvec finalize: partials -> LDS, reduce, broadcast ----
    Ph[hq][0][ho] = p0;
    Ph[hq][1][ho] = p1;
    Ph[hq][2][ho] = p2;
    __syncthreads();
    if (t < 384) {
        const int g = t >> 7, o = t & 127;
        float s = 0.f;
#pragma unroll
        for (int q = 0; q < 8; ++q) s += Ph[q][g][o];
        Hf[g][o] = s;
    }
    __syncthreads();

    // ---- epilogue: GRU combine (hvec from LDS) ----
    // C layout: col = lane&15, row = (lane>>4)*4 + reg
    float hrv[2], hzv[2], hnv[2], h0v[2];
#pragma unroll
    for (int ni = 0; ni < 2; ++ni) {
        const int ol = wn * 32 + ni * 16 + lr;     // o within slice
        hrv[ni] = Hf[0][ol];
        hzv[ni] = Hf[1][ol];
        hnv[ni] = Hf[2][ol];
        h0v[ni] = hinit[u * OFEAT + o0 + ol];
    }
    const int obase = o0 + wn * 32 + lr;
    const int rbase = b0 + wm * 32 + lg * 4;
#pragma unroll
    for (int mi = 0; mi < 2; ++mi) {
#pragma unroll
        for (int ni = 0; ni < 2; ++ni) {
            const int o = obase + ni * 16;
#pragma unroll
            for (int jj = 0; jj < 4; ++jj) {
                const int row = rbase + mi * 16 + jj;
                const float r = sigmoid_f(acc[0][mi][ni][jj] + hrv[ni]);
                const float z = sigmoid_f(acc[1][mi][ni][jj] + hzv[ni]);
                const float n = tanh_f(acc[2][mi][ni][jj] + r * hnv[ni]);
                out[((size_t)row * UNITS + u) * OFEAT + o] = (1.0f - z) * n + z * h0v[ni];
            }
        }
    }
}

extern "C" void kernel_launch(void* const* d_in, const int* in_sizes, int n_in,
                              void* d_out, int out_size, void* d_ws, size_t ws_size,
                              hipStream_t stream) {
    const float* x     = (const float*)d_in[0];
    const float* w_ir  = (const float*)d_in[1];
    const float* w_iz  = (const float*)d_in[2];
    const float* w_in  = (const float*)d_in[3];
    const float* w_hr  = (const float*)d_in[4];
    const float* w_hz  = (const float*)d_in[5];
    const float* w_hn  = (const float*)d_in[6];
    const float* hinit = (const float*)d_in[7];
    float* out = (float*)d_out;

    gru_fused<<<dim3(256), dim3(1024), 0, stream>>>(
        x, w_ir, w_iz, w_in, w_hr, w_hz, w_hn, hinit, out);
}

// Round 10
// 92.344 us; speedup vs baseline: 1.1995x; 1.1995x over previous
//
#include <hip/hip_runtime.h>
#include <hip/hip_bf16.h>

#define UNITS 64
#define IFEAT 256
#define OFEAT 256

typedef __attribute__((ext_vector_type(8))) short v8s;   // 8 bf16 (4 VGPRs)
typedef __attribute__((ext_vector_type(4))) float v4f;   // MFMA acc / global f32x4

// pack 2 floats -> u32 of 2 bf16 (RNE) — compiler emits v_cvt_pk_bf16_f32
static __device__ __forceinline__ unsigned int pk2(float a, float b) {
    union { __hip_bfloat162 h; unsigned int u; } c;
    c.h = __float22bfloat162_rn(float2{a, b});
    return c.u;
}

static __device__ __forceinline__ float sigmoid_f(float x) {
    return 1.0f / (1.0f + __expf(-x));
}
static __device__ __forceinline__ float tanh_f(float x) {
    float ax = fabsf(x);
    float e = __expf(-2.0f * ax);
    float t = (1.0f - e) / (1.0f + e);
    return copysignf(t, x);
}

// ---------------------------------------------------------------------------
// Single fused kernel: per-unit 3-way MFMA GEMM + interleaved hvec + GRU.
// BM=128, BN=128, BK=32. 1024 threads = 16 waves (4m x 4n), wave tile 32x32.
// A (x tile) full-K resident in LDS (64KB, rotated conflict-free layout).
// B (W_i) double-buffered per K-step (register-transpose, conflict-free b128).
// hvec = hinit . w_h interleaved into the K-loop (12 load+FMA per step),
// placed AFTER the MFMA section so its live range never overlaps MFMA
// operands. __launch_bounds__(1024,1): kernel is LDS-capped at 1 block/CU,
// so let the allocator use the full register file — R9's (1024,4) cap of
// 128 unified regs caused 135MB of scratch spill traffic (WRITE_SIZE 152MB).
// LDS 125.5KB -> 1 block/CU; grid 256 = 64u x 2mb x 2nb = exactly 1/CU.
// ---------------------------------------------------------------------------
__global__ __launch_bounds__(1024, 1) void gru_fused(
    const float* __restrict__ x,
    const float* __restrict__ wir,
    const float* __restrict__ wiz,
    const float* __restrict__ win,
    const float* __restrict__ whr,
    const float* __restrict__ whz,
    const float* __restrict__ whn,
    const float* __restrict__ hinit,
    float* __restrict__ out) {
    __shared__ unsigned short As[32][128][8];        // [kq][row'][j]        64 KB
    __shared__ unsigned short Bs[2][3][4][128][8];   // [buf][g][kq][col][j] 48 KB
    __shared__ float Ph[8][3][128];                  // hvec partials        12 KB
    __shared__ float Hf[3][128];                     // hvec final          1.5 KB

    const int bid = blockIdx.x;
    // XCD swizzle: xcd = bid&7 owns units [xcd*8, xcd*8+8); 4 blocks/unit.
    const int idx = bid >> 3;                  // 0..31 within XCD
    const int u   = (bid & 7) * 8 + (idx >> 2);
    const int rem = idx & 3;
    const int b0  = (rem >> 1) * 128;          // batch tile 0..1
    const int o0  = (rem & 1) * 128;           // out-feature tile 0..1

    const int t    = threadIdx.x;
    const int lane = t & 63;
    const int wv   = t >> 6;                   // 16 waves: 4m x 4n
    const int wm   = wv >> 2;                  // 0..3
    const int wn   = wv & 3;                   // 0..3
    const int lg   = lane >> 4;                // k-quad within step
    const int lr   = lane & 15;

    // ---- B staging: 1536 col-vectors/step over 1024 threads ----
    const int bcol = t & 127;
    const int bkq  = (t >> 7) & 3;
    const int gA   = t >> 9;                   // wave-uniform (0 or 1)
    const bool hasB = (wv < 8);                // wave-uniform
    const float* wpA = (gA == 0) ? wir : wiz;
    const size_t bgbase = (size_t)u * (IFEAT * OFEAT) + (bkq * 8) * OFEAT + o0 + bcol;

    float rbA[8], rbB[8];

    auto bload = [&](int kk) {
        const size_t off = bgbase + (size_t)kk * 32 * OFEAT;
#pragma unroll
        for (int j = 0; j < 8; ++j) rbA[j] = wpA[off + j * OFEAT];
        if (hasB) {
#pragma unroll
            for (int j = 0; j < 8; ++j) rbB[j] = win[off + j * OFEAT];
        }
    };
    auto bwrite = [&](int bb) {
        uint4 v;
        v.x = pk2(rbA[0], rbA[1]);
        v.y = pk2(rbA[2], rbA[3]);
        v.z = pk2(rbA[4], rbA[5]);
        v.w = pk2(rbA[6], rbA[7]);
        *(uint4*)&Bs[bb][gA][bkq][bcol][0] = v;
        if (hasB) {
            uint4 w;
            w.x = pk2(rbB[0], rbB[1]);
            w.y = pk2(rbB[2], rbB[3]);
            w.z = pk2(rbB[4], rbB[5]);
            w.w = pk2(rbB[6], rbB[7]);
            *(uint4*)&Bs[bb][2][bkq][bcol][0] = w;
        }
    };

    // ---- hvec interleave state ----
    const int ho = t & 127;                    // o-col within slice
    const int hq = t >> 7;                     // i-chunk 0..7 (wave-uniform)
    const float* hp = hinit + u * IFEAT + hq * 32;
    const size_t whbase = (size_t)u * (IFEAT * OFEAT)
                        + (size_t)(hq * 32) * OFEAT + o0 + ho;
    float p0 = 0.f, p1 = 0.f, p2 = 0.f;

    v4f acc[3][2][2];
#pragma unroll
    for (int g = 0; g < 3; ++g)
#pragma unroll
        for (int mi = 0; mi < 2; ++mi)
#pragma unroll
            for (int ni = 0; ni < 2; ++ni)
                acc[g][mi][ni] = (v4f){0.f, 0.f, 0.f, 0.f};

    // ---- prologue ----
    bload(0);                                  // B(0) in flight
    {
        // A-tile: rows coalesced (1KB row per instr), rotated frag layout
        const int kqA = lane >> 1;             // lane owns k = lane*4..+3
        const int j0  = (lane & 1) * 4;
#pragma unroll
        for (int i = 0; i < 8; ++i) {
            const int row = wv * 8 + i;
            v4f q = *(const v4f*)(x + (size_t)(b0 + row) * (UNITS * IFEAT)
                                    + u * IFEAT + lane * 4);
            uint2 w;
            w.x = pk2(q[0], q[1]);
            w.y = pk2(q[2], q[3]);
            *(uint2*)&As[kqA][(row + kqA) & 127][j0] = w;
        }
    }
    bwrite(0);
    bload(1);
    __syncthreads();

    // ---- K-loop: 8 steps, dbuf B, 1 barrier/step, hvec interleaved ----
#pragma unroll
    for (int kk = 0; kk < 8; ++kk) {
        const int bb = kk & 1;
        if (kk < 7) bwrite(bb ^ 1);        // data for kk+1 into other buffer
        if (kk < 6) bload(kk + 2);         // refill regs; lands under MFMAs

        const int kq0 = kk * 4 + lg;
        v8s a0 = *(const v8s*)&As[kq0][((wm * 32 + lr) + kq0) & 127][0];
        v8s a1 = *(const v8s*)&As[kq0][((wm * 32 + 16 + lr) + kq0) & 127][0];
#pragma unroll
        for (int g = 0; g < 3; ++g) {
#pragma unroll
            for (int ni = 0; ni < 2; ++ni) {
                v8s b = *(const v8s*)&Bs[bb][g][lg][wn * 32 + ni * 16 + lr][0];
                acc[g][0][ni] = __builtin_amdgcn_mfma_f32_16x16x32_bf16(a0, b, acc[g][0][ni], 0, 0, 0);
                acc[g][1][ni] = __builtin_amdgcn_mfma_f32_16x16x32_bf16(a1, b, acc[g][1][ni], 0, 0, 0);
            }
        }

        // hvec slice for this step (AFTER MFMAs: short live range, latency
        // covered by barrier + other waves' MFMA/staging work)
        {
            const size_t off0 = whbase + (size_t)(kk * 4) * OFEAT;
#pragma unroll
            for (int ii = 0; ii < 4; ++ii) {
                const float hi = hp[kk * 4 + ii];          // scalar (uniform)
                const size_t off = off0 + (size_t)ii * OFEAT;
                p0 += hi * whr[off];
                p1 += hi * whz[off];
                p2 += hi * whn[off];
            }
        }

        if (kk < 7) __syncthreads();       // writes(bb^1) visible, reads(bb) done
    }

    // ---- hvec finalize: partials -> LDS, reduce, broadcast ----
    Ph[hq][0][ho] = p0;
    Ph[hq][1][ho] = p1;
    Ph[hq][2][ho] = p2;
    __syncthreads();
    if (t < 384) {
        const int g = t >> 7, o = t & 127;
        float s = 0.f;
#pragma unroll
        for (int q = 0; q < 8; ++q) s += Ph[q][g][o];
        Hf[g][o] = s;
    }
    __syncthreads();

    // ---- epilogue: GRU combine (hvec from LDS) ----
    // C layout: col = lane&15, row = (lane>>4)*4 + reg
    float hrv[2], hzv[2], hnv[2], h0v[2];
#pragma unroll
    for (int ni = 0; ni < 2; ++ni) {
        const int ol = wn * 32 + ni * 16 + lr;     // o within slice
        hrv[ni] = Hf[0][ol];
        hzv[ni] = Hf[1][ol];
        hnv[ni] = Hf[2][ol];
        h0v[ni] = hinit[u * OFEAT + o0 + ol];
    }
    const int obase = o0 + wn * 32 + lr;
    const int rbase = b0 + wm * 32 + lg * 4;
#pragma unroll
    for (int mi = 0; mi < 2; ++mi) {
#pragma unroll
        for (int ni = 0; ni < 2; ++ni) {
            const int o = obase + ni * 16;
#pragma unroll
            for (int jj = 0; jj < 4; ++jj) {
                const int row = rbase + mi * 16 + jj;
                const float r = sigmoid_f(acc[0][mi][ni][jj] + hrv[ni]);
                const float z = sigmoid_f(acc[1][mi][ni][jj] + hzv[ni]);
                const float n = tanh_f(acc[2][mi][ni][jj] + r * hnv[ni]);
                out[((size_t)row * UNITS + u) * OFEAT + o] = (1.0f - z) * n + z * h0v[ni];
            }
        }
    }
}

extern "C" void kernel_launch(void* const* d_in, const int* in_sizes, int n_in,
                              void* d_out, int out_size, void* d_ws, size_t ws_size,
                              hipStream_t stream) {
    const float* x     = (const float*)d_in[0];
    const float* w_ir  = (const float*)d_in[1];
    const float* w_iz  = (const float*)d_in[2];
    const float* w_in  = (const float*)d_in[3];
    const float* w_hr  = (const float*)d_in[4];
    const float* w_hz  = (const float*)d_in[5];
    const float* w_hn  = (const float*)d_in[6];
    const float* hinit = (const float*)d_in[7];
    float* out = (float*)d_out;

    gru_fused<<<dim3(256), dim3(1024), 0, stream>>>(
        x, w_ir, w_iz, w_in, w_hr, w_hz, w_hn, hinit, out);
}

// Round 11
// 32.618 us; speedup vs baseline: 3.3959x; 2.8310x over previous
//
#include <hip/hip_runtime.h>
#include <hip/hip_bf16.h>

#define UNITS 64
#define IFEAT 256
#define OFEAT 256

typedef __attribute__((ext_vector_type(8))) short v8s;   // 8 bf16 (4 VGPRs)
typedef __attribute__((ext_vector_type(4))) float v4f;   // MFMA acc / global f32x4

// pack 2 floats -> u32 of 2 bf16 (RNE) — compiler emits v_cvt_pk_bf16_f32
static __device__ __forceinline__ unsigned int pk2(float a, float b) {
    union { __hip_bfloat162 h; unsigned int u; } c;
    c.h = __float22bfloat162_rn(float2{a, b});
    return c.u;
}

static __device__ __forceinline__ float sigmoid_f(float x) {
    return 1.0f / (1.0f + __expf(-x));
}
static __device__ __forceinline__ float tanh_f(float x) {
    float ax = fabsf(x);
    float e = __expf(-2.0f * ax);
    float t = (1.0f - e) / (1.0f + e);
    return copysignf(t, x);
}

// ---------------------------------------------------------------------------
// Single fused kernel: the GRU is ONE K=512 GEMM per gate.
//   r,z: preact = [x | h] @ [W_i ; W_h]  (h broadcast over batch)
//   n:   x@W_in and h@W_hn kept in separate accumulators (r gates the latter)
// 16 K-steps (8 x-phase + 8 h-phase) through ONE proven staging pipeline:
// B (W) double-buffered register-transpose (conflict-free b128); A from the
// 64KB rotated x-tile in x-phase, from a 512B broadcast h-tile in h-phase
// (all lanes read the same address -> LDS broadcast; result rows identical).
// No hvec side-machinery -> fits the 128-reg unified cap of 16-wave blocks.
// LDS 112.5KB -> 1 block/CU; grid 256 = 64u x 2mb x 2nb = exactly 1/CU.
// ---------------------------------------------------------------------------
__global__ __launch_bounds__(1024, 1) void gru_fused(
    const float* __restrict__ x,
    const float* __restrict__ wir,
    const float* __restrict__ wiz,
    const float* __restrict__ win,
    const float* __restrict__ whr,
    const float* __restrict__ whz,
    const float* __restrict__ whn,
    const float* __restrict__ hinit,
    float* __restrict__ out) {
    __shared__ unsigned short As[32][128][8];        // [kq][row'][j]        64 KB
    __shared__ unsigned short Bs[2][3][4][128][8];   // [buf][g][kq][col][j] 48 KB
    __shared__ unsigned short Ht[32][8];             // h broadcast tile    512 B

    const int bid = blockIdx.x;
    // XCD swizzle: xcd = bid&7 owns units [xcd*8, xcd*8+8); 4 blocks/unit.
    const int idx = bid >> 3;                  // 0..31 within XCD
    const int u   = (bid & 7) * 8 + (idx >> 2);
    const int rem = idx & 3;
    const int b0  = (rem >> 1) * 128;          // batch tile 0..1
    const int o0  = (rem & 1) * 128;           // out-feature tile 0..1

    const int t    = threadIdx.x;
    const int lane = t & 63;
    const int wv   = t >> 6;                   // 16 waves: 4m x 4n
    const int wm   = wv >> 2;                  // 0..3
    const int wn   = wv & 3;                   // 0..3
    const int lg   = lane >> 4;                // k-quad within step
    const int lr   = lane & 15;

    // ---- B staging: 1536 col-vectors/step over 1024 threads ----
    const int bcol = t & 127;
    const int bkq  = (t >> 7) & 3;
    const int gA   = t >> 9;                   // wave-uniform (0 or 1)
    const bool hasB = (wv < 8);                // wave-uniform
    const float* wpAx = (gA == 0) ? wir : wiz;
    const float* wpAh = (gA == 0) ? whr : whz;
    const size_t bgbase = (size_t)u * (IFEAT * OFEAT) + (bkq * 8) * OFEAT + o0 + bcol;

    float rbA[8], rbB[8];

    auto bload = [&](const float* pA, const float* pB, int k7) {
        const size_t off = bgbase + (size_t)k7 * 32 * OFEAT;
#pragma unroll
        for (int j = 0; j < 8; ++j) rbA[j] = pA[off + j * OFEAT];
        if (hasB) {
#pragma unroll
            for (int j = 0; j < 8; ++j) rbB[j] = pB[off + j * OFEAT];
        }
    };
    auto bwrite = [&](int bb) {
        uint4 v;
        v.x = pk2(rbA[0], rbA[1]);
        v.y = pk2(rbA[2], rbA[3]);
        v.z = pk2(rbA[4], rbA[5]);
        v.w = pk2(rbA[6], rbA[7]);
        *(uint4*)&Bs[bb][gA][bkq][bcol][0] = v;
        if (hasB) {
            uint4 w;
            w.x = pk2(rbB[0], rbB[1]);
            w.y = pk2(rbB[2], rbB[3]);
            w.z = pk2(rbB[4], rbB[5]);
            w.w = pk2(rbB[6], rbB[7]);
            *(uint4*)&Bs[bb][2][bkq][bcol][0] = w;
        }
    };

    v4f acc[3][2][2];   // r,z: full K=512 merged; n: x-part only
    v4f acch[2];        // n gate: h @ W_hn (row-independent)
#pragma unroll
    for (int g = 0; g < 3; ++g)
#pragma unroll
        for (int mi = 0; mi < 2; ++mi)
#pragma unroll
            for (int ni = 0; ni < 2; ++ni)
                acc[g][mi][ni] = (v4f){0.f, 0.f, 0.f, 0.f};
    acch[0] = (v4f){0.f, 0.f, 0.f, 0.f};
    acch[1] = (v4f){0.f, 0.f, 0.f, 0.f};

    // ---- prologue ----
    bload(wpAx, win, 0);                       // B(0) in flight
    {
        // A-tile: rows coalesced (1KB row per instr), rotated frag layout
        const int kqA = lane >> 1;             // lane owns k = lane*4..+3
        const int j0  = (lane & 1) * 4;
#pragma unroll
        for (int i = 0; i < 8; ++i) {
            const int row = wv * 8 + i;
            v4f q = *(const v4f*)(x + (size_t)(b0 + row) * (UNITS * IFEAT)
                                    + u * IFEAT + lane * 4);
            uint2 w;
            w.x = pk2(q[0], q[1]);
            w.y = pk2(q[2], q[3]);
            *(uint2*)&As[kqA][(row + kqA) & 127][j0] = w;
        }
    }
    if (t < 32) {
        // h broadcast tile: Ht[kq][j] = bf16(hinit[u, kq*8+j])
        const float* hp = hinit + u * IFEAT + t * 8;
        v4f q0 = *(const v4f*)hp;
        v4f q1 = *(const v4f*)(hp + 4);
        uint4 w;
        w.x = pk2(q0[0], q0[1]);
        w.y = pk2(q0[2], q0[3]);
        w.z = pk2(q1[0], q1[1]);
        w.w = pk2(q1[2], q1[3]);
        *(uint4*)&Ht[t][0] = w;
    }
    bwrite(0);
    bload(wpAx, win, 1);
    __syncthreads();

    // ---- K-loop: 16 steps (8 x-phase + 8 h-phase), dbuf B, 1 barrier/step
#pragma unroll
    for (int s = 0; s < 16; ++s) {
        const int bb = s & 1;
        if (s < 15) bwrite(bb ^ 1);        // data for s+1 into other buffer
        if (s < 14) {                      // refill regs for s+2
            const int ns = s + 2;
            bload(ns < 8 ? wpAx : wpAh, ns < 8 ? win : whn, ns & 7);
        }

        if (s < 8) {
            // x-phase: A from rotated x-tile
            const int kq0 = s * 4 + lg;
            v8s a0 = *(const v8s*)&As[kq0][((wm * 32 + lr) + kq0) & 127][0];
            v8s a1 = *(const v8s*)&As[kq0][((wm * 32 + 16 + lr) + kq0) & 127][0];
#pragma unroll
            for (int g = 0; g < 3; ++g) {
#pragma unroll
                for (int ni = 0; ni < 2; ++ni) {
                    v8s b = *(const v8s*)&Bs[bb][g][lg][wn * 32 + ni * 16 + lr][0];
                    acc[g][0][ni] = __builtin_amdgcn_mfma_f32_16x16x32_bf16(a0, b, acc[g][0][ni], 0, 0, 0);
                    acc[g][1][ni] = __builtin_amdgcn_mfma_f32_16x16x32_bf16(a1, b, acc[g][1][ni], 0, 0, 0);
                }
            }
        } else {
            // h-phase: A = broadcast h (all lanes same addr -> LDS broadcast)
            const int kq0 = (s - 8) * 4 + lg;
            v8s a0 = *(const v8s*)&Ht[kq0][0];
#pragma unroll
            for (int g = 0; g < 2; ++g) {      // r,z: accumulate into merged acc
#pragma unroll
                for (int ni = 0; ni < 2; ++ni) {
                    v8s b = *(const v8s*)&Bs[bb][g][lg][wn * 32 + ni * 16 + lr][0];
                    acc[g][0][ni] = __builtin_amdgcn_mfma_f32_16x16x32_bf16(a0, b, acc[g][0][ni], 0, 0, 0);
                    acc[g][1][ni] = __builtin_amdgcn_mfma_f32_16x16x32_bf16(a0, b, acc[g][1][ni], 0, 0, 0);
                }
            }
#pragma unroll
            for (int ni = 0; ni < 2; ++ni) {   // n gate: h @ W_hn separate
                v8s b = *(const v8s*)&Bs[bb][2][lg][wn * 32 + ni * 16 + lr][0];
                acch[ni] = __builtin_amdgcn_mfma_f32_16x16x32_bf16(a0, b, acch[ni], 0, 0, 0);
            }
        }

        if (s < 15) __syncthreads();       // writes(bb^1) visible, reads(bb) done
    }

    // ---- epilogue: GRU combine (h-terms live in the accumulators) ----
    // C layout: col = lane&15, row = (lane>>4)*4 + reg
    float h0v[2];
#pragma unroll
    for (int ni = 0; ni < 2; ++ni)
        h0v[ni] = hinit[u * OFEAT + o0 + wn * 32 + ni * 16 + lr];

    const int obase = o0 + wn * 32 + lr;
    const int rbase = b0 + wm * 32 + lg * 4;
#pragma unroll
    for (int mi = 0; mi < 2; ++mi) {
#pragma unroll
        for (int ni = 0; ni < 2; ++ni) {
            const int o = obase + ni * 16;
#pragma unroll
            for (int jj = 0; jj < 4; ++jj) {
                const int row = rbase + mi * 16 + jj;
                const float r = sigmoid_f(acc[0][mi][ni][jj]);
                const float z = sigmoid_f(acc[1][mi][ni][jj]);
                const float n = tanh_f(acc[2][mi][ni][jj] + r * acch[ni][jj]);
                out[((size_t)row * UNITS + u) * OFEAT + o] = (1.0f - z) * n + z * h0v[ni];
            }
        }
    }
}

extern "C" void kernel_launch(void* const* d_in, const int* in_sizes, int n_in,
                              void* d_out, int out_size, void* d_ws, size_t ws_size,
                              hipStream_t stream) {
    const float* x     = (const float*)d_in[0];
    const float* w_ir  = (const float*)d_in[1];
    const float* w_iz  = (const float*)d_in[2];
    const float* w_in  = (const float*)d_in[3];
    const float* w_hr  = (const float*)d_in[4];
    const float* w_hz  = (const float*)d_in[5];
    const float* w_hn  = (const float*)d_in[6];
    const float* hinit = (const float*)d_in[7];
    float* out = (float*)d_out;

    gru_fused<<<dim3(256), dim3(1024), 0, stream>>>(
        x, w_ir, w_iz, w_in, w_hr, w_hz, w_hn, hinit, out);
}

// Round 12
// 32.472 us; speedup vs baseline: 3.4112x; 1.0045x over previous
//
#include <hip/hip_runtime.h>
#include <hip/hip_bf16.h>

#define UNITS 64
#define IFEAT 256
#define OFEAT 256

typedef __attribute__((ext_vector_type(8))) short v8s;   // 8 bf16 (4 VGPRs)
typedef __attribute__((ext_vector_type(4))) float v4f;   // MFMA acc / global f32x4

// pack 2 floats -> u32 of 2 bf16 (RNE) — compiler emits v_cvt_pk_bf16_f32
static __device__ __forceinline__ unsigned int pk2(float a, float b) {
    union { __hip_bfloat162 h; unsigned int u; } c;
    c.h = __float22bfloat162_rn(float2{a, b});
    return c.u;
}

static __device__ __forceinline__ float sigmoid_f(float x) {
    return 1.0f / (1.0f + __expf(-x));
}
static __device__ __forceinline__ float tanh_f(float x) {
    float ax = fabsf(x);
    float e = __expf(-2.0f * ax);
    float t = (1.0f - e) / (1.0f + e);
    return copysignf(t, x);
}

// ---------------------------------------------------------------------------
// Single fused kernel, BARRIER-FREE K-loop.
//   r,z: preact = [x | h] @ [W_i ; W_h]  (K=512, h broadcast over batch)
//   n:   x@W_in in acc[2]; h@W_hn in acch (r gates it in the epilogue)
// 512 threads = 8 waves, wave tile 128x16: each wave OWNS its 16 output
// cols, loads its own B fragment directly global->reg->cvt->MFMA (lane=col,
// 8 strided dwords per gate per step; B read exactly once). A (x) lives in
// the rotated LDS tile (read-only after the single prologue barrier); the
// h-phase A comes from a 512B broadcast tile. No Bs LDS, no ds_writes, no
// per-step barriers -> waves drift freely and pipes overlap (fixes the
// additive-pipe lockstep measured in R4..R11).
// 2 waves/SIMD -> 256-reg cap: acc 100 + B dbl-buf 48 + a-frags 32 + addr
// ~20 ≈ 200, no spill (WRITE_SIZE is the sentinel).
// LDS 64.5KB; grid 256 = 64u x 2mb x 2nb = 1 block/CU, XCD-swizzled.
// ---------------------------------------------------------------------------
__global__ __launch_bounds__(512, 1) void gru_fused(
    const float* __restrict__ x,
    const float* __restrict__ wir,
    const float* __restrict__ wiz,
    const float* __restrict__ win,
    const float* __restrict__ whr,
    const float* __restrict__ whz,
    const float* __restrict__ whn,
    const float* __restrict__ hinit,
    float* __restrict__ out) {
    __shared__ unsigned short As[32][128][8];        // [kq][row'][j]   64 KB
    __shared__ unsigned short Ht[32][8];             // h broadcast    512 B

    const int bid = blockIdx.x;
    // XCD swizzle: xcd = bid&7 owns units [xcd*8, xcd*8+8); 4 blocks/unit.
    const int idx = bid >> 3;                  // 0..31 within XCD
    const int u   = (bid & 7) * 8 + (idx >> 2);
    const int rem = idx & 3;
    const int b0  = (rem >> 1) * 128;          // batch tile 0..1
    const int o0  = (rem & 1) * 128;           // out-feature tile 0..1

    const int t    = threadIdx.x;
    const int lane = t & 63;
    const int wv   = t >> 6;                   // 8 waves = 8 col-slices
    const int lg   = lane >> 4;                // k-group 0..3
    const int lr   = lane & 15;

    const float* WX[3] = {wir, wiz, win};
    const float* WH[3] = {whr, whz, whn};

    // ---- prologue: stage A (rotated frag layout) + Ht, ONE barrier ----
    {
        const int kqA = lane >> 1;             // lane owns k = lane*4..+3
        const int j0  = (lane & 1) * 4;
#pragma unroll
        for (int i = 0; i < 16; ++i) {
            const int row = wv * 16 + i;
            v4f q = *(const v4f*)(x + (size_t)(b0 + row) * (UNITS * IFEAT)
                                    + u * IFEAT + lane * 4);
            uint2 w;
            w.x = pk2(q[0], q[1]);
            w.y = pk2(q[2], q[3]);
            *(uint2*)&As[kqA][(row + kqA) & 127][j0] = w;
        }
    }
    if (t < 32) {
        const float* hp = hinit + u * IFEAT + t * 8;
        v4f q0 = *(const v4f*)hp;
        v4f q1 = *(const v4f*)(hp + 4);
        uint4 w;
        w.x = pk2(q0[0], q0[1]);
        w.y = pk2(q0[2], q0[3]);
        w.z = pk2(q1[0], q1[1]);
        w.w = pk2(q1[2], q1[3]);
        *(uint4*)&Ht[t][0] = w;
    }

    // per-thread B base offset (col = o0 + wv*16 + lr owned by this lane)
    const size_t bcolofs = (size_t)u * (IFEAT * OFEAT) + o0 + wv * 16 + lr;

    float rbA[3][8], rbB[3][8];                // 1-step rotate (static idx)

#define LOADB(dst, s)                                                        \
    {                                                                        \
        const float* const* W = ((s) < 8) ? WX : WH;                         \
        const size_t boff = bcolofs + (size_t)(((s) & 7) * 4 + lg) * 8 * OFEAT; \
        _Pragma("unroll")                                                    \
        for (int g = 0; g < 3; ++g) {                                        \
            const float* p = W[g] + boff;                                    \
            _Pragma("unroll")                                                \
            for (int j = 0; j < 8; ++j) dst[g][j] = p[j * OFEAT];            \
        }                                                                    \
    }

    v4f acc[3][8];                             // [gate][mi], ni = 1
    v4f acch;                                  // n gate: h @ W_hn
#pragma unroll
    for (int g = 0; g < 3; ++g)
#pragma unroll
        for (int mi = 0; mi < 8; ++mi)
            acc[g][mi] = (v4f){0.f, 0.f, 0.f, 0.f};
    acch = (v4f){0.f, 0.f, 0.f, 0.f};

    LOADB(rbA, 0);                             // prefetch step 0
    __syncthreads();                           // the ONLY barrier

    // ---- K-loop: 16 steps (8 x-phase + 8 h-phase), barrier-free ----
#pragma unroll
    for (int s = 0; s < 16; ++s) {
        // prefetch next step's B while computing this one
        if (s < 15) {
            if (s & 1) { LOADB(rbA, s + 1); }
            else       { LOADB(rbB, s + 1); }
        }
        const float (*rb)[8] = (s & 1) ? rbB : rbA;

        // cvt this step's B to bf16 fragments
        v8s bf[3];
#pragma unroll
        for (int g = 0; g < 3; ++g) {
            uint4 v;
            v.x = pk2(rb[g][0], rb[g][1]);
            v.y = pk2(rb[g][2], rb[g][3]);
            v.z = pk2(rb[g][4], rb[g][5]);
            v.w = pk2(rb[g][6], rb[g][7]);
            union { uint4 u4; v8s s8; } cv;
            cv.u4 = v;
            bf[g] = cv.s8;
        }

        const int kq = (s & 7) * 4 + lg;
        if (s < 8) {
            // x-phase: 8 a-frags from rotated LDS tile
#pragma unroll
            for (int mi = 0; mi < 8; ++mi) {
                v8s a = *(const v8s*)&As[kq][((mi * 16 + lr) + kq) & 127][0];
#pragma unroll
                for (int g = 0; g < 3; ++g)
                    acc[g][mi] = __builtin_amdgcn_mfma_f32_16x16x32_bf16(
                        a, bf[g], acc[g][mi], 0, 0, 0);
            }
        } else {
            // h-phase: broadcast A (all rows identical)
            v8s a0h = *(const v8s*)&Ht[kq][0];
#pragma unroll
            for (int g = 0; g < 2; ++g)
#pragma unroll
                for (int mi = 0; mi < 8; ++mi)
                    acc[g][mi] = __builtin_amdgcn_mfma_f32_16x16x32_bf16(
                        a0h, bf[g], acc[g][mi], 0, 0, 0);
            acch = __builtin_amdgcn_mfma_f32_16x16x32_bf16(a0h, bf[2], acch, 0, 0, 0);
        }
    }
#undef LOADB

    // ---- epilogue: GRU combine ----
    // C layout: col = lane&15, row = (lane>>4)*4 + reg
    const int o = o0 + wv * 16 + lr;
    const float h0v = hinit[u * OFEAT + o];
#pragma unroll
    for (int mi = 0; mi < 8; ++mi) {
#pragma unroll
        for (int jj = 0; jj < 4; ++jj) {
            const int row = b0 + mi * 16 + lg * 4 + jj;
            const float r = sigmoid_f(acc[0][mi][jj]);
            const float z = sigmoid_f(acc[1][mi][jj]);
            const float n = tanh_f(acc[2][mi][jj] + r * acch[jj]);
            out[(size_t)row * (UNITS * OFEAT) + u * OFEAT + o] =
                (1.0f - z) * n + z * h0v;
        }
    }
}

extern "C" void kernel_launch(void* const* d_in, const int* in_sizes, int n_in,
                              void* d_out, int out_size, void* d_ws, size_t ws_size,
                              hipStream_t stream) {
    const float* x     = (const float*)d_in[0];
    const float* w_ir  = (const float*)d_in[1];
    const float* w_iz  = (const float*)d_in[2];
    const float* w_in  = (const float*)d_in[3];
    const float* w_hr  = (const float*)d_in[4];
    const float* w_hz  = (const float*)d_in[5];
    const float* w_hn  = (const float*)d_in[6];
    const float* hinit = (const float*)d_in[7];
    float* out = (float*)d_out;

    gru_fused<<<dim3(256), dim3(512), 0, stream>>>(
        x, w_ir, w_iz, w_in, w_hr, w_hz, w_hn, hinit, out);
}